// Round 1
// baseline (678.114 us; speedup 1.0000x reference)
//
#include <hip/hip_runtime.h>
#include <hip/hip_bf16.h>

// Problem constants
static constexpr int cB  = 16;
static constexpr int cS  = 512;
static constexpr int cD  = 256;
static constexpr int cH  = 8;
static constexpr int cDH = 32;
static constexpr int cQT = 16;   // q rows per attention block
static constexpr int cKT = 64;   // k tile

// ---------------------------------------------------------------------------
// Projection: C = X @ W^T + b, stored as (B,H,S,DH) into ws.
// grid (8192/128, 256/128, 3), block 256. 128x128 tile, BK=32, swizzled LDS.
// ---------------------------------------------------------------------------
__global__ __launch_bounds__(256) void proj_kernel(
    const float* __restrict__ q_in, const float* __restrict__ k_in,
    const float* __restrict__ v_in,
    const float* __restrict__ Wq, const float* __restrict__ bq,
    const float* __restrict__ Wk, const float* __restrict__ bk,
    const float* __restrict__ Wv, const float* __restrict__ bv,
    float* __restrict__ ws)
{
    const int z = blockIdx.z;
    const float* X    = (z == 0) ? q_in : (z == 1) ? k_in : v_in;
    const float* W    = (z == 0) ? Wq   : (z == 1) ? Wk   : Wv;
    const float* bias = (z == 0) ? bq   : (z == 1) ? bk   : bv;
    float* O = ws + (size_t)z * (cB * cS * cD);

    __shared__ float Xs[128 * 36];
    __shared__ float Wsh[128 * 36];

    const int tid = threadIdx.x;
    const int i0 = blockIdx.x * 128;
    const int j0 = blockIdx.y * 128;

    float acc[8][8];
#pragma unroll
    for (int i = 0; i < 8; i++)
#pragma unroll
        for (int j = 0; j < 8; j++) acc[i][j] = 0.f;

    for (int k0 = 0; k0 < cD; k0 += 32) {
#pragma unroll
        for (int l = 0; l < 4; l++) {
            int idx = tid + l * 256;
            int r = idx >> 3, g = idx & 7;
            float4 xv = *(const float4*)&X[(size_t)(i0 + r) * cD + k0 + g * 4];
            float4 wv = *(const float4*)&W[(size_t)(j0 + r) * cD + k0 + g * 4];
            int gs = ((g ^ ((r >> 3) & 7)) << 2);
            *(float4*)&Xs[r * 36 + gs]  = xv;
            *(float4*)&Wsh[r * 36 + gs] = wv;
        }
        __syncthreads();
        const int ty = tid >> 4, tx = tid & 15;
#pragma unroll
        for (int kk = 0; kk < 32; kk += 4) {
            int g = kk >> 2;
            float4 a[8], bb[8];
#pragma unroll
            for (int i = 0; i < 8; i++) {
                int r = ty * 8 + i;
                a[i] = *(const float4*)&Xs[r * 36 + ((g ^ ((r >> 3) & 7)) << 2)];
            }
#pragma unroll
            for (int j = 0; j < 8; j++) {
                int r = tx * 8 + j;
                bb[j] = *(const float4*)&Wsh[r * 36 + ((g ^ ((r >> 3) & 7)) << 2)];
            }
#pragma unroll
            for (int i = 0; i < 8; i++)
#pragma unroll
                for (int j = 0; j < 8; j++)
                    acc[i][j] += a[i].x * bb[j].x + a[i].y * bb[j].y +
                                 a[i].z * bb[j].z + a[i].w * bb[j].w;
        }
        __syncthreads();
    }

    const int ty = tid >> 4, tx = tid & 15;
#pragma unroll
    for (int i = 0; i < 8; i++) {
        int gi = i0 + ty * 8 + i;
        int b_ = gi >> 9, s_ = gi & 511;
        int jbase = j0 + tx * 8;
        int h_ = jbase >> 5, dh0 = jbase & 31;
        float vals[8];
#pragma unroll
        for (int j = 0; j < 8; j++) vals[j] = acc[i][j] + bias[jbase + j];
        float* dst = O + (((size_t)(b_ * cH + h_) * cS + s_) * cDH + dh0);
        *(float4*)dst       = make_float4(vals[0], vals[1], vals[2], vals[3]);
        *(float4*)(dst + 4) = make_float4(vals[4], vals[5], vals[6], vals[7]);
    }
}

// ---------------------------------------------------------------------------
// Attention: one block per (b, q-tile of 16). All 8 heads computed in-block.
// Ev = (1-l1)*l2*T + l1*R computed once (head-independent), stored bf16.
// ---------------------------------------------------------------------------
__global__ __launch_bounds__(256) void attn_kernel(
    const float* __restrict__ ws,
    const float* __restrict__ rel, const float* __restrict__ ts,
    const float* __restrict__ l1p, const float* __restrict__ l2p,
    float* __restrict__ out, float* __restrict__ prob)
{
    const int qt  = blockIdx.x;   // 0..31
    const int b   = blockIdx.y;   // 0..15
    const int q0  = qt * cQT;
    const int tid = threadIdx.x;

    const float* qh = ws;
    const float* kh = ws + (size_t)cB * cS * cD;
    const float* vh = ws + (size_t)2 * cB * cS * cD;

    __shared__ float Pc[cQT][cS + 4];            // 16 x 516 f32
    __shared__ __hip_bfloat16 Ev[cQT][cS + 8];   // 16 x 520 bf16
    __shared__ float Qs[cQT][cDH];
    __shared__ float KVs[cKT][cDH + 4];          // 64 x 36
    __shared__ float Outs[cQT][cDH];

    const float l1 = l1p[0], l2 = l2p[0];
    const float Ac = (1.f - l1) * (1.f - l2);
    const float Bc = (1.f - l1) * l2;
    const float Cc = l1;

    // ---- E phase: head-independent time/rel softmaxes ----
    {
        const int q = tid >> 4, lane = tid & 15;
        const int qg = q0 + q;
        const float* ts_row  = ts  + ((size_t)b * cS + qg) * cS;
        const float* rel_row = rel + ((size_t)b * cS + qg) * cS;

        float tmax = -1e30f, rmax = -1e30f;
        for (int k = lane; k < cS; k += 16) {
            if (k <= qg) tmax = fmaxf(tmax, __expf(-fabsf(ts_row[k])));
            float rv = rel_row[k];
            rv = (k > qg && rv != 0.f) ? rv : -10000.f;
            rmax = fmaxf(rmax, rv);
        }
#pragma unroll
        for (int m = 1; m < 16; m <<= 1) {
            tmax = fmaxf(tmax, __shfl_xor(tmax, m, 16));
            rmax = fmaxf(rmax, __shfl_xor(rmax, m, 16));
        }
        float tsum = 0.f, rsum = 0.f;
        for (int k = lane; k < cS; k += 16) {
            if (k <= qg) tsum += __expf(__expf(-fabsf(ts_row[k])) - tmax);
            float rv = rel_row[k];
            rv = (k > qg && rv != 0.f) ? rv : -10000.f;
            rsum += __expf(rv - rmax);
        }
#pragma unroll
        for (int m = 1; m < 16; m <<= 1) {
            tsum += __shfl_xor(tsum, m, 16);
            rsum += __shfl_xor(rsum, m, 16);
        }
        const float tinv = Bc / tsum;
        const float rinv = Cc / rsum;
        for (int k = lane; k < cS; k += 16) {
            float e = 0.f;
            if (k <= qg) e = __expf(__expf(-fabsf(ts_row[k])) - tmax) * tinv;
            float rv = rel_row[k];
            rv = (k > qg && rv != 0.f) ? rv : -10000.f;
            e += __expf(rv - rmax) * rinv;
            Ev[q][k] = __float2bfloat16(e);
        }
    }
    __syncthreads();

    const int kt_max = (q0 + cQT - 1) / cKT;   // last score tile (inclusive)

    for (int h = 0; h < cH; h++) {
        const size_t bh = (size_t)(b * cH + h);

        // stage Q tile; zero Outs
        if (tid < 128) {
            int r = tid >> 3, g = tid & 7;
            *(float4*)&Qs[r][g * 4] =
                *(const float4*)&qh[(bh * cS + q0 + r) * cDH + g * 4];
        } else {
            int idx = tid - 128;  // 128 float4 = 512 floats
            ((float4*)&Outs[0][0])[idx] = make_float4(0.f, 0.f, 0.f, 0.f);
        }
        __syncthreads();

        // Q rows qp and qp+8 into registers
        const int qp = tid >> 5;       // 0..7
        const int lane32 = tid & 31;
        float4 qa[8], qb[8];
#pragma unroll
        for (int u = 0; u < 8; u++) {
            qa[u] = *(const float4*)&Qs[qp][u * 4];
            qb[u] = *(const float4*)&Qs[qp + 8][u * 4];
        }

        // ---- scores: QK^T / sqrt(32) for needed tiles ----
        for (int kt = 0; kt <= kt_max; kt++) {
            int k0 = kt * cKT;
            __syncthreads();
#pragma unroll
            for (int l = 0; l < 2; l++) {
                int idx = tid + l * 256;
                int r = idx >> 3, g = idx & 7;
                *(float4*)&KVs[r][g * 4] =
                    *(const float4*)&kh[(bh * cS + k0 + r) * cDH + g * 4];
            }
            __syncthreads();
#pragma unroll
            for (int j = 0; j < 2; j++) {
                int kk = lane32 + j * 32;
                float sa = 0.f, sb = 0.f;
#pragma unroll
                for (int u = 0; u < 8; u++) {
                    float4 kv = *(const float4*)&KVs[kk][u * 4];
                    sa += qa[u].x * kv.x + qa[u].y * kv.y + qa[u].z * kv.z + qa[u].w * kv.w;
                    sb += qb[u].x * kv.x + qb[u].y * kv.y + qb[u].z * kv.z + qb[u].w * kv.w;
                }
                Pc[qp][k0 + kk]     = sa * 0.1767766952966369f;
                Pc[qp + 8][k0 + kk] = sb * 0.1767766952966369f;
            }
        }
        __syncthreads();

        // ---- in-place softmax over k<=qg, blend with Ev ----
        {
            const int q = tid >> 4, lane = tid & 15;
            const int qg = q0 + q;
            float smax = -1e30f;
            for (int k = lane; k <= qg; k += 16) smax = fmaxf(smax, Pc[q][k]);
#pragma unroll
            for (int m = 1; m < 16; m <<= 1) smax = fmaxf(smax, __shfl_xor(smax, m, 16));
            float ssum = 0.f;
            for (int k = lane; k <= qg; k += 16) {
                float e = __expf(Pc[q][k] - smax);
                Pc[q][k] = e;
                ssum += e;
            }
#pragma unroll
            for (int m = 1; m < 16; m <<= 1) ssum += __shfl_xor(ssum, m, 16);
            const float pinv = Ac / ssum;
            for (int k = lane; k < cS; k += 16) {
                float v = (k <= qg) ? Pc[q][k] * pinv : 0.f;
                v += __bfloat162float(Ev[q][k]);
                Pc[q][k] = v;
            }
        }
        __syncthreads();

        // ---- write prob_attn rows (coalesced float4) ----
        {
            float* prow = prob + bh * cS * cS + (size_t)q0 * cS;
#pragma unroll
            for (int l = 0; l < 8; l++) {
                int idx = tid + l * 256;       // 0..2047
                int q = idx >> 7, f = idx & 127;
                float4 v = *(const float4*)&Pc[q][f * 4];
                *(float4*)&prow[(size_t)q * cS + f * 4] = v;
            }
        }

        // ---- PV: out[q][d] = sum_k Pc[q][k] * V[k][d] ----
        const int ks = tid >> 5;         // 0..7  (k slice in tile)
        const int qq = (tid >> 3) & 3;   // 0..3  (4 q rows)
        const int d4 = tid & 7;          // 0..7  (4 d cols)
        float4 acc[4];
#pragma unroll
        for (int i = 0; i < 4; i++) acc[i] = make_float4(0.f, 0.f, 0.f, 0.f);

        for (int kt = 0; kt < cS / cKT; kt++) {
            int k0 = kt * cKT;
            __syncthreads();
#pragma unroll
            for (int l = 0; l < 2; l++) {
                int idx = tid + l * 256;
                int r = idx >> 3, g = idx & 7;
                *(float4*)&KVs[r][g * 4] =
                    *(const float4*)&vh[(bh * cS + k0 + r) * cDH + g * 4];
            }
            __syncthreads();
#pragma unroll
            for (int c = 0; c < 2; c++) {
                int kk = ks * 8 + c * 4;
                float4 vv[4];
#pragma unroll
                for (int x = 0; x < 4; x++)
                    vv[x] = *(const float4*)&KVs[kk + x][d4 * 4];
#pragma unroll
                for (int qi = 0; qi < 4; qi++) {
                    float4 p = *(const float4*)&Pc[qq * 4 + qi][k0 + kk];
                    acc[qi].x += p.x * vv[0].x + p.y * vv[1].x + p.z * vv[2].x + p.w * vv[3].x;
                    acc[qi].y += p.x * vv[0].y + p.y * vv[1].y + p.z * vv[2].y + p.w * vv[3].y;
                    acc[qi].z += p.x * vv[0].z + p.y * vv[1].z + p.z * vv[2].z + p.w * vv[3].z;
                    acc[qi].w += p.x * vv[0].w + p.y * vv[1].w + p.z * vv[2].w + p.w * vv[3].w;
                }
            }
        }
#pragma unroll
        for (int qi = 0; qi < 4; qi++) {
            atomicAdd(&Outs[qq * 4 + qi][d4 * 4 + 0], acc[qi].x);
            atomicAdd(&Outs[qq * 4 + qi][d4 * 4 + 1], acc[qi].y);
            atomicAdd(&Outs[qq * 4 + qi][d4 * 4 + 2], acc[qi].z);
            atomicAdd(&Outs[qq * 4 + qi][d4 * 4 + 3], acc[qi].w);
        }
        __syncthreads();
        if (tid < 128) {
            int q = tid >> 3, dd = tid & 7;
            float4 v = *(const float4*)&Outs[q][dd * 4];
            *(float4*)&out[((size_t)b * cS + q0 + q) * cD + h * cDH + dd * 4] = v;
        }
        __syncthreads();   // before next head reuses Qs/Outs/Pc/KVs
    }
}

extern "C" void kernel_launch(void* const* d_in, const int* in_sizes, int n_in,
                              void* d_out, int out_size, void* d_ws, size_t ws_size,
                              hipStream_t stream) {
    const float* query = (const float*)d_in[0];
    const float* key   = (const float*)d_in[1];
    const float* value = (const float*)d_in[2];
    const float* rel   = (const float*)d_in[3];
    const float* tsp   = (const float*)d_in[4];
    // d_in[5] = mask: strictly-upper-triangular, computed from indices instead
    const float* l1 = (const float*)d_in[6];
    const float* l2 = (const float*)d_in[7];
    const float* Wq = (const float*)d_in[8];
    const float* bq = (const float*)d_in[9];
    const float* Wk = (const float*)d_in[10];
    const float* bk = (const float*)d_in[11];
    const float* Wv = (const float*)d_in[12];
    const float* bv = (const float*)d_in[13];

    float* ws   = (float*)d_ws;                       // q,k,v projected: 24 MB
    float* out  = (float*)d_out;                      // (B,S,D)
    float* prob = out + (size_t)cB * cS * cD;         // (B,H,S,S)

    proj_kernel<<<dim3(64, 2, 3), 256, 0, stream>>>(query, key, value,
                                                    Wq, bq, Wk, bk, Wv, bv, ws);
    attn_kernel<<<dim3(32, 16), 256, 0, stream>>>(ws, rel, tsp, l1, l2, out, prob);
}

// Round 2
// 559.050 us; speedup vs baseline: 1.2130x; 1.2130x over previous
//
#include <hip/hip_runtime.h>
#include <hip/hip_bf16.h>

static constexpr int cB  = 16;
static constexpr int cS  = 512;
static constexpr int cD  = 256;
static constexpr int cH  = 8;
static constexpr int cDH = 32;

typedef __attribute__((ext_vector_type(8))) short short8v;
typedef __attribute__((ext_vector_type(4))) float f32x4;

__device__ __forceinline__ short bfbits(float x) {
    __hip_bfloat16 h = __float2bfloat16(x);
    short s; __builtin_memcpy(&s, &h, 2); return s;
}
__device__ __forceinline__ float bff(short s) {
    __hip_bfloat16 h; __builtin_memcpy(&h, &s, 2); return __bfloat162float(h);
}

// ---------------------------------------------------------------------------
// Projection: C = X @ W^T + b, stored as (B,H,S,DH) into ws. (unchanged)
// ---------------------------------------------------------------------------
__global__ __launch_bounds__(256) void proj_kernel(
    const float* __restrict__ q_in, const float* __restrict__ k_in,
    const float* __restrict__ v_in,
    const float* __restrict__ Wq, const float* __restrict__ bq,
    const float* __restrict__ Wk, const float* __restrict__ bk,
    const float* __restrict__ Wv, const float* __restrict__ bv,
    float* __restrict__ ws)
{
    const int z = blockIdx.z;
    const float* X    = (z == 0) ? q_in : (z == 1) ? k_in : v_in;
    const float* W    = (z == 0) ? Wq   : (z == 1) ? Wk   : Wv;
    const float* bias = (z == 0) ? bq   : (z == 1) ? bk   : bv;
    float* O = ws + (size_t)z * (cB * cS * cD);

    __shared__ float Xs[128 * 36];
    __shared__ float Wsh[128 * 36];

    const int tid = threadIdx.x;
    const int i0 = blockIdx.x * 128;
    const int j0 = blockIdx.y * 128;

    float acc[8][8];
#pragma unroll
    for (int i = 0; i < 8; i++)
#pragma unroll
        for (int j = 0; j < 8; j++) acc[i][j] = 0.f;

    for (int k0 = 0; k0 < cD; k0 += 32) {
#pragma unroll
        for (int l = 0; l < 4; l++) {
            int idx = tid + l * 256;
            int r = idx >> 3, g = idx & 7;
            float4 xv = *(const float4*)&X[(size_t)(i0 + r) * cD + k0 + g * 4];
            float4 wv = *(const float4*)&W[(size_t)(j0 + r) * cD + k0 + g * 4];
            int gs = ((g ^ ((r >> 3) & 7)) << 2);
            *(float4*)&Xs[r * 36 + gs]  = xv;
            *(float4*)&Wsh[r * 36 + gs] = wv;
        }
        __syncthreads();
        const int ty = tid >> 4, tx = tid & 15;
#pragma unroll
        for (int kk = 0; kk < 32; kk += 4) {
            int g = kk >> 2;
            float4 a[8], bb[8];
#pragma unroll
            for (int i = 0; i < 8; i++) {
                int r = ty * 8 + i;
                a[i] = *(const float4*)&Xs[r * 36 + ((g ^ ((r >> 3) & 7)) << 2)];
            }
#pragma unroll
            for (int j = 0; j < 8; j++) {
                int r = tx * 8 + j;
                bb[j] = *(const float4*)&Wsh[r * 36 + ((g ^ ((r >> 3) & 7)) << 2)];
            }
#pragma unroll
            for (int i = 0; i < 8; i++)
#pragma unroll
                for (int j = 0; j < 8; j++)
                    acc[i][j] += a[i].x * bb[j].x + a[i].y * bb[j].y +
                                 a[i].z * bb[j].z + a[i].w * bb[j].w;
        }
        __syncthreads();
    }

    const int ty = tid >> 4, tx = tid & 15;
#pragma unroll
    for (int i = 0; i < 8; i++) {
        int gi = i0 + ty * 8 + i;
        int b_ = gi >> 9, s_ = gi & 511;
        int jbase = j0 + tx * 8;
        int h_ = jbase >> 5, dh0 = jbase & 31;
        float vals[8];
#pragma unroll
        for (int j = 0; j < 8; j++) vals[j] = acc[i][j] + bias[jbase + j];
        float* dst = O + (((size_t)(b_ * cH + h_) * cS + s_) * cDH + dh0);
        *(float4*)dst       = make_float4(vals[0], vals[1], vals[2], vals[3]);
        *(float4*)(dst + 4) = make_float4(vals[4], vals[5], vals[6], vals[7]);
    }
}

// ---------------------------------------------------------------------------
// Ev kernel: Ev[b][q][k] = Bc*time_attn + Cc*rel_attn  (head-independent),
// stored bf16. One wave per (b,q) row.
// ---------------------------------------------------------------------------
__global__ __launch_bounds__(256) void ev_kernel(
    const float* __restrict__ rel, const float* __restrict__ ts,
    const float* __restrict__ l1p, const float* __restrict__ l2p,
    short* __restrict__ Evb)
{
    const int w = threadIdx.x >> 6, lane = threadIdx.x & 63;
    const int row = blockIdx.x * 4 + w;          // b*512 + q
    const int q = row & 511;
    const float* tr = ts  + (size_t)row * cS;
    const float* rr = rel + (size_t)row * cS;
    const float l1 = l1p[0], l2 = l2p[0];
    const float Bc = (1.f - l1) * l2;
    const float Cc = l1;

    float tv[8], rv[8];
    float tmax = -1e30f, rmax = -1e30f;
#pragma unroll
    for (int j = 0; j < 8; j++) {
        int k = lane + 64 * j;
        float t = __expf(-fabsf(tr[k]));
        float r = rr[k];
        r = (k > q && r != 0.f) ? r : -10000.f;
        tv[j] = (k <= q) ? t : -1e30f;
        rv[j] = r;
        tmax = fmaxf(tmax, tv[j]);
        rmax = fmaxf(rmax, r);
    }
#pragma unroll
    for (int m = 1; m < 64; m <<= 1) {
        tmax = fmaxf(tmax, __shfl_xor(tmax, m, 64));
        rmax = fmaxf(rmax, __shfl_xor(rmax, m, 64));
    }
    float te[8], re[8];
    float tsum = 0.f, rsum = 0.f;
#pragma unroll
    for (int j = 0; j < 8; j++) {
        te[j] = (tv[j] > -1e29f) ? __expf(tv[j] - tmax) : 0.f;
        re[j] = __expf(rv[j] - rmax);
        tsum += te[j]; rsum += re[j];
    }
#pragma unroll
    for (int m = 1; m < 64; m <<= 1) {
        tsum += __shfl_xor(tsum, m, 64);
        rsum += __shfl_xor(rsum, m, 64);
    }
    const float ti = Bc / tsum, ri = Cc / rsum;
#pragma unroll
    for (int j = 0; j < 8; j++) {
        int k = lane + 64 * j;
        Evb[(size_t)row * cS + k] = bfbits(te[j] * ti + re[j] * ri);
    }
}

// ---------------------------------------------------------------------------
// Attention v2: one block per (b,h,32-q-tile). MFMA QK^T (bf16 hi/lo split),
// in-register softmax, P through LDS bf16, coalesced prob writes, MFMA PV.
// ---------------------------------------------------------------------------
__global__ __launch_bounds__(256) void attn2_kernel(
    const float* __restrict__ ws, const short* __restrict__ Evb,
    const float* __restrict__ l1p, const float* __restrict__ l2p,
    float* __restrict__ out, float* __restrict__ prob)
{
    constexpr int PS = 536;                       // P row stride (bf16 elems)
    __shared__ short Pl[32 * PS];                 // 33.5 KB
    __shared__ float redM[2][32];
    __shared__ float redS[2][32];

    const int tid  = threadIdx.x;
    const int w    = tid >> 6;
    const int lane = tid & 63;
    const int n16  = lane & 15;
    const int quad = lane >> 4;

    const int qt = blockIdx.x;                    // 0..15
    const size_t bh = blockIdx.y;                 // b*8 + h
    const int h = blockIdx.y & 7;
    const int b = blockIdx.y >> 3;
    const int q0 = qt * 32;

    const float* qh = ws;
    const float* kh = ws + (size_t)cB * cS * cD;
    const float* vh = ws + 2 * (size_t)cB * cS * cD;

    const float l1 = l1p[0], l2 = l2p[0];
    const float Ac = (1.f - l1) * (1.f - l2);

    const int qhH = w & 1;                        // which 16 q rows
    const int kh2 = w >> 1;                       // which 256 keys
    const int kbase = 256 * kh2;

    // ---- A fragment: Q rows (hi/lo bf16 split) ----
    const int rowA = q0 + 16 * qhH + n16;
    const float* qrow = qh + (bh * cS + rowA) * cDH + quad * 8;
    float qa[8];
    *(float4*)&qa[0] = *(const float4*)qrow;
    *(float4*)&qa[4] = *(const float4*)(qrow + 4);
    short8v a_hi, a_lo;
#pragma unroll
    for (int j = 0; j < 8; j++) {
        short hbits = bfbits(qa[j]);
        a_hi[j] = hbits;
        a_lo[j] = bfbits(qa[j] - bff(hbits));
    }

    // ---- QK^T MFMA over this wave's 16 key tiles ----
    f32x4 acc[16];
#pragma unroll
    for (int t = 0; t < 16; t++) acc[t] = (f32x4){0.f, 0.f, 0.f, 0.f};

    const int tl = (kbase <= q0 + 31) ? min(15, (q0 + 31 - kbase) >> 4) : -1;
    for (int t = 0; t <= tl; t++) {
        const float* krow = kh + (bh * cS + kbase + 16 * t + n16) * cDH + quad * 8;
        float kb[8];
        *(float4*)&kb[0] = *(const float4*)krow;
        *(float4*)&kb[4] = *(const float4*)(krow + 4);
        short8v b_hi, b_lo;
#pragma unroll
        for (int j = 0; j < 8; j++) {
            short hbits = bfbits(kb[j]);
            b_hi[j] = hbits;
            b_lo[j] = bfbits(kb[j] - bff(hbits));
        }
        acc[t] = __builtin_amdgcn_mfma_f32_16x16x32_bf16(a_hi, b_hi, acc[t], 0, 0, 0);
        acc[t] = __builtin_amdgcn_mfma_f32_16x16x32_bf16(a_hi, b_lo, acc[t], 0, 0, 0);
        acc[t] = __builtin_amdgcn_mfma_f32_16x16x32_bf16(a_lo, b_hi, acc[t], 0, 0, 0);
    }

    // ---- mask + scale + row max (rows rowD = q0+16*qhH+quad*4+r) ----
    const float scale = 0.17677669529663687f;
    const int rowDl = 16 * qhH + quad * 4;        // local row base (0..28)
    float Mx0 = -1e30f, Mx1 = -1e30f, Mx2 = -1e30f, Mx3 = -1e30f;
#pragma unroll
    for (int t = 0; t < 16; t++) {
        const int kg = kbase + 16 * t + n16;
        const int rg = q0 + rowDl;
        float s0 = (kg <= rg + 0) ? acc[t][0] * scale : -1e30f;
        float s1 = (kg <= rg + 1) ? acc[t][1] * scale : -1e30f;
        float s2 = (kg <= rg + 2) ? acc[t][2] * scale : -1e30f;
        float s3 = (kg <= rg + 3) ? acc[t][3] * scale : -1e30f;
        acc[t][0] = s0; acc[t][1] = s1; acc[t][2] = s2; acc[t][3] = s3;
        Mx0 = fmaxf(Mx0, s0); Mx1 = fmaxf(Mx1, s1);
        Mx2 = fmaxf(Mx2, s2); Mx3 = fmaxf(Mx3, s3);
    }
#pragma unroll
    for (int m = 1; m < 16; m <<= 1) {
        Mx0 = fmaxf(Mx0, __shfl_xor(Mx0, m, 64));
        Mx1 = fmaxf(Mx1, __shfl_xor(Mx1, m, 64));
        Mx2 = fmaxf(Mx2, __shfl_xor(Mx2, m, 64));
        Mx3 = fmaxf(Mx3, __shfl_xor(Mx3, m, 64));
    }
    if (n16 == 0) {
        redM[kh2][rowDl + 0] = Mx0; redM[kh2][rowDl + 1] = Mx1;
        redM[kh2][rowDl + 2] = Mx2; redM[kh2][rowDl + 3] = Mx3;
    }
    __syncthreads();
    float Mg0 = fmaxf(redM[0][rowDl + 0], redM[1][rowDl + 0]);
    float Mg1 = fmaxf(redM[0][rowDl + 1], redM[1][rowDl + 1]);
    float Mg2 = fmaxf(redM[0][rowDl + 2], redM[1][rowDl + 2]);
    float Mg3 = fmaxf(redM[0][rowDl + 3], redM[1][rowDl + 3]);

    // ---- exp + row sum ----
    float S0 = 0.f, S1 = 0.f, S2 = 0.f, S3 = 0.f;
#pragma unroll
    for (int t = 0; t < 16; t++) {
        float e0 = __expf(acc[t][0] - Mg0);
        float e1 = __expf(acc[t][1] - Mg1);
        float e2 = __expf(acc[t][2] - Mg2);
        float e3 = __expf(acc[t][3] - Mg3);
        acc[t][0] = e0; acc[t][1] = e1; acc[t][2] = e2; acc[t][3] = e3;
        S0 += e0; S1 += e1; S2 += e2; S3 += e3;
    }
#pragma unroll
    for (int m = 1; m < 16; m <<= 1) {
        S0 += __shfl_xor(S0, m, 64); S1 += __shfl_xor(S1, m, 64);
        S2 += __shfl_xor(S2, m, 64); S3 += __shfl_xor(S3, m, 64);
    }
    if (n16 == 0) {
        redS[kh2][rowDl + 0] = S0; redS[kh2][rowDl + 1] = S1;
        redS[kh2][rowDl + 2] = S2; redS[kh2][rowDl + 3] = S3;
    }
    __syncthreads();
    const float i0 = Ac / (redS[0][rowDl + 0] + redS[1][rowDl + 0]);
    const float i1 = Ac / (redS[0][rowDl + 1] + redS[1][rowDl + 1]);
    const float i2 = Ac / (redS[0][rowDl + 2] + redS[1][rowDl + 2]);
    const float i3 = Ac / (redS[0][rowDl + 3] + redS[1][rowDl + 3]);

    // ---- store softmax part to P (bf16) ----
#pragma unroll
    for (int t = 0; t < 16; t++) {
        const int col = kbase + 16 * t + n16;
        Pl[(rowDl + 0) * PS + col] = bfbits(acc[t][0] * i0);
        Pl[(rowDl + 1) * PS + col] = bfbits(acc[t][1] * i1);
        Pl[(rowDl + 2) * PS + col] = bfbits(acc[t][2] * i2);
        Pl[(rowDl + 3) * PS + col] = bfbits(acc[t][3] * i3);
    }
    __syncthreads();

    // ---- blend with Ev + coalesced prob write + P write-back ----
#pragma unroll
    for (int it = 0; it < 8; it++) {
        const int idx = it * 256 + tid;
        const int r = idx >> 6;
        const int c0 = (idx & 63) * 8;
        short* pp = &Pl[r * PS + c0];
        short8v pv = *(short8v*)pp;
        const short* ep = Evb + ((size_t)(b * cS + q0 + r)) * cS + c0;
        short8v ev = *(const short8v*)ep;
        float o[8];
#pragma unroll
        for (int j = 0; j < 8; j++) o[j] = bff(pv[j]) + bff(ev[j]);
        float* pr = prob + (bh * cS + q0 + r) * cS + c0;
        *(float4*)pr       = make_float4(o[0], o[1], o[2], o[3]);
        *(float4*)(pr + 4) = make_float4(o[4], o[5], o[6], o[7]);
#pragma unroll
        for (int j = 0; j < 8; j++) pv[j] = bfbits(o[j]);
        *(short8v*)pp = pv;
    }
    __syncthreads();

    // ---- PV: out^T(32x32) = V^T(32x512) @ P^T(512x32), 1 tile per wave ----
    const int dhT = w & 1, qT = w >> 1;
    const int dhA = 16 * dhT + n16;
    f32x4 oacc = (f32x4){0.f, 0.f, 0.f, 0.f};
    for (int k0 = 0; k0 < cS; k0 += 32) {
        const float* vp = vh + (bh * cS + k0 + quad * 8) * cDH + dhA;
        short8v av;
#pragma unroll
        for (int j = 0; j < 8; j++) av[j] = bfbits(vp[j * cDH]);
        short8v bv = *(short8v*)&Pl[(16 * qT + n16) * PS + k0 + quad * 8];
        oacc = __builtin_amdgcn_mfma_f32_16x16x32_bf16(av, bv, oacc, 0, 0, 0);
    }
    const int qg = q0 + 16 * qT + n16;
    const int dhD = 16 * dhT + quad * 4;
    float* op = out + ((size_t)b * cS + qg) * cD + h * cDH + dhD;
    op[0] = oacc[0]; op[1] = oacc[1]; op[2] = oacc[2]; op[3] = oacc[3];
}

extern "C" void kernel_launch(void* const* d_in, const int* in_sizes, int n_in,
                              void* d_out, int out_size, void* d_ws, size_t ws_size,
                              hipStream_t stream) {
    const float* query = (const float*)d_in[0];
    const float* key   = (const float*)d_in[1];
    const float* value = (const float*)d_in[2];
    const float* rel   = (const float*)d_in[3];
    const float* tsp   = (const float*)d_in[4];
    const float* l1 = (const float*)d_in[6];
    const float* l2 = (const float*)d_in[7];
    const float* Wq = (const float*)d_in[8];
    const float* bq = (const float*)d_in[9];
    const float* Wk = (const float*)d_in[10];
    const float* bk = (const float*)d_in[11];
    const float* Wv = (const float*)d_in[12];
    const float* bv = (const float*)d_in[13];

    float* ws   = (float*)d_ws;
    short* Evb  = (short*)(ws + 3 * (size_t)cB * cS * cD);   // bf16, 8.4 MB
    float* out  = (float*)d_out;
    float* prob = out + (size_t)cB * cS * cD;

    proj_kernel<<<dim3(64, 2, 3), 256, 0, stream>>>(query, key, value,
                                                    Wq, bq, Wk, bk, Wv, bv, ws);
    ev_kernel<<<dim3(2048), 256, 0, stream>>>(rel, tsp, l1, l2, Evb);
    attn2_kernel<<<dim3(16, 128), 256, 0, stream>>>(ws, Evb, l1, l2, out, prob);
}

// Round 3
// 422.634 us; speedup vs baseline: 1.6045x; 1.3228x over previous
//
#include <hip/hip_runtime.h>
#include <hip/hip_bf16.h>

static constexpr int cB  = 16;
static constexpr int cS  = 512;
static constexpr int cD  = 256;
static constexpr int cH  = 8;
static constexpr int cDH = 32;

typedef __attribute__((ext_vector_type(8))) short short8v;
typedef __attribute__((ext_vector_type(4))) float f32x4;

__device__ __forceinline__ short bfbits(float x) {
    __hip_bfloat16 h = __float2bfloat16(x);
    short s; __builtin_memcpy(&s, &h, 2); return s;
}
__device__ __forceinline__ float bff(short s) {
    __hip_bfloat16 h; __builtin_memcpy(&h, &s, 2); return __bfloat162float(h);
}

// ---------------------------------------------------------------------------
// Projection v2: C = X @ W^T + b via bf16 hi/lo MFMA (f32-grade accuracy).
// grid (8192/32, 3), block 256 (4 waves). No LDS. W fragments come from L2.
// Output stored as (B,H,S,DH) into ws.
// ---------------------------------------------------------------------------
__global__ __launch_bounds__(256) void proj_kernel(
    const float* __restrict__ q_in, const float* __restrict__ k_in,
    const float* __restrict__ v_in,
    const float* __restrict__ Wq, const float* __restrict__ bq,
    const float* __restrict__ Wk, const float* __restrict__ bk,
    const float* __restrict__ Wv, const float* __restrict__ bv,
    float* __restrict__ ws)
{
    const int z = blockIdx.y;
    const float* X    = (z == 0) ? q_in : (z == 1) ? k_in : v_in;
    const float* W    = (z == 0) ? Wq   : (z == 1) ? Wk   : Wv;
    const float* bias = (z == 0) ? bq   : (z == 1) ? bk   : bv;
    float* O = ws + (size_t)z * (cB * cS * cD);

    const int tid  = threadIdx.x;
    const int w    = tid >> 6;
    const int lane = tid & 63;
    const int n16  = lane & 15;
    const int quad = lane >> 4;

    const int i0 = blockIdx.x * 32 + 16 * (w & 1);   // wave's 16-row group
    const int j0 = 128 * (w >> 1);                   // wave's 128-col half

    // ---- A fragments: X rows, full K=256, bf16 hi/lo ----
    const float* xrow = X + (size_t)(i0 + n16) * cD + quad * 8;
    short8v a_hi[8], a_lo[8];
#pragma unroll
    for (int c = 0; c < 8; c++) {
        float xa[8];
        *(float4*)&xa[0] = *(const float4*)(xrow + c * 32);
        *(float4*)&xa[4] = *(const float4*)(xrow + c * 32 + 4);
#pragma unroll
        for (int j = 0; j < 8; j++) {
            short hb = bfbits(xa[j]);
            a_hi[c][j] = hb;
            a_lo[c][j] = bfbits(xa[j] - bff(hb));
        }
    }

    // ---- 8 col tiles of 16x16, K-chunks of 32 ----
#pragma unroll
    for (int t = 0; t < 8; t++) {
        const int jb = j0 + t * 16;
        const float* wrow = W + (size_t)(jb + n16) * cD + quad * 8;
        f32x4 acc = (f32x4){0.f, 0.f, 0.f, 0.f};
#pragma unroll
        for (int c = 0; c < 8; c++) {
            float wv_[8];
            *(float4*)&wv_[0] = *(const float4*)(wrow + c * 32);
            *(float4*)&wv_[4] = *(const float4*)(wrow + c * 32 + 4);
            short8v b_hi, b_lo;
#pragma unroll
            for (int j = 0; j < 8; j++) {
                short hb = bfbits(wv_[j]);
                b_hi[j] = hb;
                b_lo[j] = bfbits(wv_[j] - bff(hb));
            }
            acc = __builtin_amdgcn_mfma_f32_16x16x32_bf16(a_hi[c], b_hi, acc, 0, 0, 0);
            acc = __builtin_amdgcn_mfma_f32_16x16x32_bf16(a_hi[c], b_lo, acc, 0, 0, 0);
            acc = __builtin_amdgcn_mfma_f32_16x16x32_bf16(a_lo[c], b_hi, acc, 0, 0, 0);
        }
        // D: row = i0 + quad*4 + r, col = jb + n16
        const int jg = jb + n16;
        const float bv_ = bias[jg];
        const int h_ = jg >> 5, dh = jg & 31;
#pragma unroll
        for (int r = 0; r < 4; r++) {
            int gi = i0 + quad * 4 + r;
            int b_ = gi >> 9, s_ = gi & 511;
            O[(((size_t)(b_ * cH + h_)) * cS + s_) * cDH + dh] = acc[r] + bv_;
        }
    }
}

// ---------------------------------------------------------------------------
// Ev kernel: Ev[b][q][k] = Bc*time_attn + Cc*rel_attn  (head-independent),
// stored bf16. One wave per (b,q) row.
// ---------------------------------------------------------------------------
__global__ __launch_bounds__(256) void ev_kernel(
    const float* __restrict__ rel, const float* __restrict__ ts,
    const float* __restrict__ l1p, const float* __restrict__ l2p,
    short* __restrict__ Evb)
{
    const int w = threadIdx.x >> 6, lane = threadIdx.x & 63;
    const int row = blockIdx.x * 4 + w;          // b*512 + q
    const int q = row & 511;
    const float* tr = ts  + (size_t)row * cS;
    const float* rr = rel + (size_t)row * cS;
    const float l1 = l1p[0], l2 = l2p[0];
    const float Bc = (1.f - l1) * l2;
    const float Cc = l1;

    float tv[8], rv[8];
    float tmax = -1e30f, rmax = -1e30f;
#pragma unroll
    for (int j = 0; j < 8; j++) {
        int k = lane + 64 * j;
        float t = __expf(-fabsf(tr[k]));
        float r = rr[k];
        r = (k > q && r != 0.f) ? r : -10000.f;
        tv[j] = (k <= q) ? t : -1e30f;
        rv[j] = r;
        tmax = fmaxf(tmax, tv[j]);
        rmax = fmaxf(rmax, r);
    }
#pragma unroll
    for (int m = 1; m < 64; m <<= 1) {
        tmax = fmaxf(tmax, __shfl_xor(tmax, m, 64));
        rmax = fmaxf(rmax, __shfl_xor(rmax, m, 64));
    }
    float te[8], re[8];
    float tsum = 0.f, rsum = 0.f;
#pragma unroll
    for (int j = 0; j < 8; j++) {
        te[j] = (tv[j] > -1e29f) ? __expf(tv[j] - tmax) : 0.f;
        re[j] = __expf(rv[j] - rmax);
        tsum += te[j]; rsum += re[j];
    }
#pragma unroll
    for (int m = 1; m < 64; m <<= 1) {
        tsum += __shfl_xor(tsum, m, 64);
        rsum += __shfl_xor(rsum, m, 64);
    }
    const float ti = Bc / tsum, ri = Cc / rsum;
#pragma unroll
    for (int j = 0; j < 8; j++) {
        int k = lane + 64 * j;
        Evb[(size_t)row * cS + k] = bfbits(te[j] * ti + re[j] * ri);
    }
}

// ---------------------------------------------------------------------------
// Attention v2: one block per (b,h,32-q-tile). MFMA QK^T (bf16 hi/lo split),
// in-register softmax, P through LDS bf16, coalesced prob writes, MFMA PV.
// ---------------------------------------------------------------------------
__global__ __launch_bounds__(256) void attn2_kernel(
    const float* __restrict__ ws, const short* __restrict__ Evb,
    const float* __restrict__ l1p, const float* __restrict__ l2p,
    float* __restrict__ out, float* __restrict__ prob)
{
    constexpr int PS = 536;                       // P row stride (bf16 elems)
    __shared__ short Pl[32 * PS];                 // 33.5 KB
    __shared__ float redM[2][32];
    __shared__ float redS[2][32];

    const int tid  = threadIdx.x;
    const int w    = tid >> 6;
    const int lane = tid & 63;
    const int n16  = lane & 15;
    const int quad = lane >> 4;

    const int qt = blockIdx.x;                    // 0..15
    const size_t bh = blockIdx.y;                 // b*8 + h
    const int h = blockIdx.y & 7;
    const int b = blockIdx.y >> 3;
    const int q0 = qt * 32;

    const float* qh = ws;
    const float* kh = ws + (size_t)cB * cS * cD;
    const float* vh = ws + 2 * (size_t)cB * cS * cD;

    const float l1 = l1p[0], l2 = l2p[0];
    const float Ac = (1.f - l1) * (1.f - l2);

    const int qhH = w & 1;                        // which 16 q rows
    const int kh2 = w >> 1;                       // which 256 keys
    const int kbase = 256 * kh2;

    // ---- A fragment: Q rows (hi/lo bf16 split) ----
    const int rowA = q0 + 16 * qhH + n16;
    const float* qrow = qh + (bh * cS + rowA) * cDH + quad * 8;
    float qa[8];
    *(float4*)&qa[0] = *(const float4*)qrow;
    *(float4*)&qa[4] = *(const float4*)(qrow + 4);
    short8v a_hi, a_lo;
#pragma unroll
    for (int j = 0; j < 8; j++) {
        short hbits = bfbits(qa[j]);
        a_hi[j] = hbits;
        a_lo[j] = bfbits(qa[j] - bff(hbits));
    }

    // ---- QK^T MFMA over this wave's 16 key tiles ----
    f32x4 acc[16];
#pragma unroll
    for (int t = 0; t < 16; t++) acc[t] = (f32x4){0.f, 0.f, 0.f, 0.f};

    const int tl = (kbase <= q0 + 31) ? min(15, (q0 + 31 - kbase) >> 4) : -1;
    for (int t = 0; t <= tl; t++) {
        const float* krow = kh + (bh * cS + kbase + 16 * t + n16) * cDH + quad * 8;
        float kb[8];
        *(float4*)&kb[0] = *(const float4*)krow;
        *(float4*)&kb[4] = *(const float4*)(krow + 4);
        short8v b_hi, b_lo;
#pragma unroll
        for (int j = 0; j < 8; j++) {
            short hbits = bfbits(kb[j]);
            b_hi[j] = hbits;
            b_lo[j] = bfbits(kb[j] - bff(hbits));
        }
        acc[t] = __builtin_amdgcn_mfma_f32_16x16x32_bf16(a_hi, b_hi, acc[t], 0, 0, 0);
        acc[t] = __builtin_amdgcn_mfma_f32_16x16x32_bf16(a_hi, b_lo, acc[t], 0, 0, 0);
        acc[t] = __builtin_amdgcn_mfma_f32_16x16x32_bf16(a_lo, b_hi, acc[t], 0, 0, 0);
    }

    // ---- mask + scale + row max (rows rowD = q0+16*qhH+quad*4+r) ----
    const float scale = 0.17677669529663687f;
    const int rowDl = 16 * qhH + quad * 4;        // local row base (0..28)
    float Mx0 = -1e30f, Mx1 = -1e30f, Mx2 = -1e30f, Mx3 = -1e30f;
#pragma unroll
    for (int t = 0; t < 16; t++) {
        const int kg = kbase + 16 * t + n16;
        const int rg = q0 + rowDl;
        float s0 = (kg <= rg + 0) ? acc[t][0] * scale : -1e30f;
        float s1 = (kg <= rg + 1) ? acc[t][1] * scale : -1e30f;
        float s2 = (kg <= rg + 2) ? acc[t][2] * scale : -1e30f;
        float s3 = (kg <= rg + 3) ? acc[t][3] * scale : -1e30f;
        acc[t][0] = s0; acc[t][1] = s1; acc[t][2] = s2; acc[t][3] = s3;
        Mx0 = fmaxf(Mx0, s0); Mx1 = fmaxf(Mx1, s1);
        Mx2 = fmaxf(Mx2, s2); Mx3 = fmaxf(Mx3, s3);
    }
#pragma unroll
    for (int m = 1; m < 16; m <<= 1) {
        Mx0 = fmaxf(Mx0, __shfl_xor(Mx0, m, 64));
        Mx1 = fmaxf(Mx1, __shfl_xor(Mx1, m, 64));
        Mx2 = fmaxf(Mx2, __shfl_xor(Mx2, m, 64));
        Mx3 = fmaxf(Mx3, __shfl_xor(Mx3, m, 64));
    }
    if (n16 == 0) {
        redM[kh2][rowDl + 0] = Mx0; redM[kh2][rowDl + 1] = Mx1;
        redM[kh2][rowDl + 2] = Mx2; redM[kh2][rowDl + 3] = Mx3;
    }
    __syncthreads();
    float Mg0 = fmaxf(redM[0][rowDl + 0], redM[1][rowDl + 0]);
    float Mg1 = fmaxf(redM[0][rowDl + 1], redM[1][rowDl + 1]);
    float Mg2 = fmaxf(redM[0][rowDl + 2], redM[1][rowDl + 2]);
    float Mg3 = fmaxf(redM[0][rowDl + 3], redM[1][rowDl + 3]);

    // ---- exp + row sum ----
    float S0 = 0.f, S1 = 0.f, S2 = 0.f, S3 = 0.f;
#pragma unroll
    for (int t = 0; t < 16; t++) {
        float e0 = __expf(acc[t][0] - Mg0);
        float e1 = __expf(acc[t][1] - Mg1);
        float e2 = __expf(acc[t][2] - Mg2);
        float e3 = __expf(acc[t][3] - Mg3);
        acc[t][0] = e0; acc[t][1] = e1; acc[t][2] = e2; acc[t][3] = e3;
        S0 += e0; S1 += e1; S2 += e2; S3 += e3;
    }
#pragma unroll
    for (int m = 1; m < 16; m <<= 1) {
        S0 += __shfl_xor(S0, m, 64); S1 += __shfl_xor(S1, m, 64);
        S2 += __shfl_xor(S2, m, 64); S3 += __shfl_xor(S3, m, 64);
    }
    if (n16 == 0) {
        redS[kh2][rowDl + 0] = S0; redS[kh2][rowDl + 1] = S1;
        redS[kh2][rowDl + 2] = S2; redS[kh2][rowDl + 3] = S3;
    }
    __syncthreads();
    const float i0 = Ac / (redS[0][rowDl + 0] + redS[1][rowDl + 0]);
    const float i1 = Ac / (redS[0][rowDl + 1] + redS[1][rowDl + 1]);
    const float i2 = Ac / (redS[0][rowDl + 2] + redS[1][rowDl + 2]);
    const float i3 = Ac / (redS[0][rowDl + 3] + redS[1][rowDl + 3]);

    // ---- store softmax part to P (bf16) ----
#pragma unroll
    for (int t = 0; t < 16; t++) {
        const int col = kbase + 16 * t + n16;
        Pl[(rowDl + 0) * PS + col] = bfbits(acc[t][0] * i0);
        Pl[(rowDl + 1) * PS + col] = bfbits(acc[t][1] * i1);
        Pl[(rowDl + 2) * PS + col] = bfbits(acc[t][2] * i2);
        Pl[(rowDl + 3) * PS + col] = bfbits(acc[t][3] * i3);
    }
    __syncthreads();

    // ---- blend with Ev + coalesced prob write + P write-back ----
#pragma unroll
    for (int it = 0; it < 8; it++) {
        const int idx = it * 256 + tid;
        const int r = idx >> 6;
        const int c0 = (idx & 63) * 8;
        short* pp = &Pl[r * PS + c0];
        short8v pv = *(short8v*)pp;
        const short* ep = Evb + ((size_t)(b * cS + q0 + r)) * cS + c0;
        short8v ev = *(const short8v*)ep;
        float o[8];
#pragma unroll
        for (int j = 0; j < 8; j++) o[j] = bff(pv[j]) + bff(ev[j]);
        float* pr = prob + (bh * cS + q0 + r) * cS + c0;
        *(float4*)pr       = make_float4(o[0], o[1], o[2], o[3]);
        *(float4*)(pr + 4) = make_float4(o[4], o[5], o[6], o[7]);
#pragma unroll
        for (int j = 0; j < 8; j++) pv[j] = bfbits(o[j]);
        *(short8v*)pp = pv;
    }
    __syncthreads();

    // ---- PV: out^T(32x32) = V^T(32x512) @ P^T(512x32), 1 tile per wave ----
    const int dhT = w & 1, qT = w >> 1;
    const int dhA = 16 * dhT + n16;
    f32x4 oacc = (f32x4){0.f, 0.f, 0.f, 0.f};
    for (int k0 = 0; k0 < cS; k0 += 32) {
        const float* vp = vh + (bh * cS + k0 + quad * 8) * cDH + dhA;
        short8v av;
#pragma unroll
        for (int j = 0; j < 8; j++) av[j] = bfbits(vp[j * cDH]);
        short8v bv = *(short8v*)&Pl[(16 * qT + n16) * PS + k0 + quad * 8];
        oacc = __builtin_amdgcn_mfma_f32_16x16x32_bf16(av, bv, oacc, 0, 0, 0);
    }
    const int qg = q0 + 16 * qT + n16;
    const int dhD = 16 * dhT + quad * 4;
    float* op = out + ((size_t)b * cS + qg) * cD + h * cDH + dhD;
    op[0] = oacc[0]; op[1] = oacc[1]; op[2] = oacc[2]; op[3] = oacc[3];
}

extern "C" void kernel_launch(void* const* d_in, const int* in_sizes, int n_in,
                              void* d_out, int out_size, void* d_ws, size_t ws_size,
                              hipStream_t stream) {
    const float* query = (const float*)d_in[0];
    const float* key   = (const float*)d_in[1];
    const float* value = (const float*)d_in[2];
    const float* rel   = (const float*)d_in[3];
    const float* tsp   = (const float*)d_in[4];
    const float* l1 = (const float*)d_in[6];
    const float* l2 = (const float*)d_in[7];
    const float* Wq = (const float*)d_in[8];
    const float* bq = (const float*)d_in[9];
    const float* Wk = (const float*)d_in[10];
    const float* bk = (const float*)d_in[11];
    const float* Wv = (const float*)d_in[12];
    const float* bv = (const float*)d_in[13];

    float* ws   = (float*)d_ws;
    short* Evb  = (short*)(ws + 3 * (size_t)cB * cS * cD);   // bf16, 8.4 MB
    float* out  = (float*)d_out;
    float* prob = out + (size_t)cB * cS * cD;

    proj_kernel<<<dim3(256, 3), 256, 0, stream>>>(query, key, value,
                                                  Wq, bq, Wk, bk, Wv, bv, ws);
    ev_kernel<<<dim3(2048), 256, 0, stream>>>(rel, tsp, l1, l2, Evb);
    attn2_kernel<<<dim3(16, 128), 256, 0, stream>>>(ws, Evb, l1, l2, out, prob);
}